// Round 10
// baseline (615.261 us; speedup 1.0000x reference)
//
#include <hip/hip_runtime.h>

typedef _Float16 half8 __attribute__((ext_vector_type(8)));
typedef _Float16 hv4 __attribute__((ext_vector_type(4)));
typedef float fv4 __attribute__((ext_vector_type(4)));

typedef __attribute__((address_space(3))) unsigned lds_u32;
typedef const __attribute__((address_space(1))) unsigned glb_u32;

// async global->LDS, 16B per lane; dst is wave-uniform base, HW adds lane*16B
__device__ __forceinline__ void gll16(const void* g, void* l) {
  __builtin_amdgcn_global_load_lds((glb_u32*)g, (lds_u32*)l, 16, 0, 0);
}

// ---------------------------------------------------------------- LayerNorm
__global__ __launch_bounds__(256) void ln_rows(const float* __restrict__ in,
                                               const float* __restrict__ g,
                                               const float* __restrict__ bb,
                                               _Float16* __restrict__ out, int ncols) {
  __shared__ float sm[8];
  int row = blockIdx.x, t = threadIdx.x;
  const float* rp = in + (size_t)row * ncols;
  int nv = ncols >> 10;
  fv4 v[2];
  float s1 = 0.f, s2 = 0.f;
#pragma unroll
  for (int c = 0; c < 2; ++c)
    if (c < nv) {
      v[c] = *(const fv4*)(rp + c * 1024 + t * 4);
#pragma unroll
      for (int j = 0; j < 4; ++j) { s1 += v[c][j]; s2 += v[c][j] * v[c][j]; }
    }
#pragma unroll
  for (int off = 32; off > 0; off >>= 1) { s1 += __shfl_xor(s1, off, 64); s2 += __shfl_xor(s2, off, 64); }
  int w = t >> 6;
  if ((t & 63) == 0) { sm[w] = s1; sm[4 + w] = s2; }
  __syncthreads();
  s1 = sm[0] + sm[1] + sm[2] + sm[3];
  s2 = sm[4] + sm[5] + sm[6] + sm[7];
  float inv = 1.0f / (float)ncols;
  float mu = s1 * inv;
  float var = s2 * inv - mu * mu;
  float rstd = rsqrtf(var + 1e-5f);
#pragma unroll
  for (int c = 0; c < 2; ++c)
    if (c < nv) {
      int col = c * 1024 + t * 4;
      fv4 gg = *(const fv4*)(g + col);
      fv4 bv = *(const fv4*)(bb + col);
      hv4 o;
#pragma unroll
      for (int j = 0; j < 4; ++j) o[j] = (_Float16)(((v[c][j] - mu) * rstd) * gg[j] + bv[j]);
      *(hv4*)(out + (size_t)row * ncols + col) = o;
    }
}

// ---------------------------------------------------------------- fp32 -> fp16 cast
__global__ __launch_bounds__(256) void cast_f16(const float* __restrict__ in,
                                                _Float16* __restrict__ out, int n) {
  int i = (blockIdx.x * 256 + threadIdx.x) << 2;
  if (i < n) {
    fv4 f = *(const fv4*)(in + i);
    hv4 h;
#pragma unroll
    for (int j = 0; j < 4; ++j) h[j] = (_Float16)f[j];
    *(hv4*)(out + i) = h;
  }
}

// ---------------------------------------------------------------- sum ns partials -> fp16
__global__ __launch_bounds__(256) void reduce_split(const float* __restrict__ parts, int ns,
                                                    long long stride,
                                                    _Float16* __restrict__ hi, int n) {
  int i = (blockIdx.x * 256 + threadIdx.x) << 2;
  if (i < n) {
    fv4 s = *(const fv4*)(parts + i);
    for (int j = 1; j < ns; ++j) {
      fv4 v = *(const fv4*)(parts + (size_t)j * stride + i);
      s += v;
    }
    hv4 h;
#pragma unroll
    for (int j = 0; j < 4; ++j) h[j] = (_Float16)s[j];
    *(hv4*)(hi + i) = h;
  }
}

// ---------------------------------------------------------------- fused Hopfield step
// One block per (strip of 16 xi rows, head, batch). Phases:
//  1) scores(16x2048) = beta * xi_strip(16x128) @ K_h^T  -> LDS fp16 (padded stride 2056)
//  2) entmax-1.5 tau per row (Michelot + LDS compaction), c = m/2 + tau -> LDS
//  3) xi_strip = w(16x2048) @ V_h  (w recomputed on the fly from LDS scores + c),
//     fp32 MFMA accumulation over full K, direct fp16 store (in-place: this block is
//     the only reader/writer of its 16-row x 128-col head slice, read-before-write).
// MFMA layouts (16x16x32): A[m=lane&15][k=quad*8+j], B[n=lane&15][k=quad*8+j],
// C: col=lane&15, row=quad*4+reg.
#define SST 2056  // LDS score row stride in halves (16B-aligned; banks spread by 4/row)
__global__ __launch_bounds__(256, 2) void hop_step(const _Float16* __restrict__ xi,
                                                   const _Float16* __restrict__ kp,
                                                   const _Float16* __restrict__ vt,
                                                   const float* __restrict__ log_beta,
                                                   _Float16* __restrict__ xout) {
  __shared__ __align__(16) _Float16 Ss[16 * SST];
  __shared__ float comp[4][512];
  __shared__ float cs[16];
  int strip = blockIdx.x, h = blockIdx.y, b = blockIdx.z;
  int t = threadIdx.x, wv = t >> 6, l = t & 63;
  int quad = l >> 4, lr = l & 15;
  unsigned long long lmask = (1ull << l) - 1ull;
  float beta = __expf(log_beta[h]);

  const _Float16* xiA = xi + ((size_t)(b * 1024 + strip * 16)) * 1024 + h * 128;
  const _Float16* Kb = kp + h * 128;
  const _Float16* Vb = vt + (size_t)h * 128 * 2048;

  // ---- phase 1: QK^T
  half8 af[4];
#pragma unroll
  for (int ki = 0; ki < 4; ++ki)
    af[ki] = *(const half8*)(xiA + (size_t)lr * 1024 + ki * 32 + quad * 8);
  for (int nt = wv * 32; nt < wv * 32 + 32; ++nt) {
    int n0 = nt * 16;
    fv4 acc = {};
#pragma unroll
    for (int ki = 0; ki < 4; ++ki) {
      half8 bf = *(const half8*)(Kb + (size_t)(n0 + lr) * 1024 + ki * 32 + quad * 8);
      acc = __builtin_amdgcn_mfma_f32_16x16x32_f16(af[ki], bf, acc, 0, 0, 0);
    }
#pragma unroll
    for (int r = 0; r < 4; ++r)
      Ss[(quad * 4 + r) * SST + n0 + lr] = (_Float16)(acc[r] * beta);
  }
  __syncthreads();

  // ---- phase 2: entmax tau per row (wave wv owns rows wv*4 .. wv*4+3)
  for (int rr = 0; rr < 4; ++rr) {
    int row = wv * 4 + rr;
    const half8* rp = (const half8*)&Ss[row * SST];
    half8 hx[4];
#pragma unroll
    for (int i = 0; i < 4; ++i) hx[i] = rp[i * 64 + l];
    fv4 x[8];
#pragma unroll
    for (int i = 0; i < 4; ++i)
#pragma unroll
      for (int j = 0; j < 8; ++j) x[i * 2 + (j >> 2)][j & 3] = (float)hx[i][j];
    float m = x[0][0];
#pragma unroll
    for (int i = 0; i < 8; ++i)
#pragma unroll
      for (int j = 0; j < 4; ++j) m = fmaxf(m, x[i][j]);
#pragma unroll
    for (int off = 32; off > 0; off >>= 1) m = fmaxf(m, __shfl_xor(m, off, 64));
#pragma unroll
    for (int i = 0; i < 8; ++i)
#pragma unroll
      for (int j = 0; j < 4; ++j) x[i][j] = (x[i][j] - m) * 0.5f;

    float tau = -1.0f;
    bool fixed = false;
    int cnti = 2048;
    for (int it = 0; it < 6 && !fixed; ++it) {
      float s1 = 0.f, s2 = 0.f;
      cnti = 0;
#pragma unroll
      for (int i = 0; i < 8; ++i)
#pragma unroll
        for (int j = 0; j < 4; ++j) {
          bool a = x[i][j] > tau;
          cnti += (int)__builtin_popcountll(__ballot(a));
          float sel = a ? x[i][j] : 0.f;
          s1 += sel;
          s2 = fmaf(sel, sel, s2);
        }
#pragma unroll
      for (int off = 32; off > 0; off >>= 1) {
        s1 += __shfl_xor(s1, off, 64);
        s2 += __shfl_xor(s2, off, 64);
      }
      float cnt = (float)cnti;
      float mean = s1 / cnt;
      float ss = s2 - s1 * mean;
      float nt = mean - sqrtf(fmaxf((1.0f - ss) / cnt, 0.0f));
      if (nt == tau) fixed = true;
      else tau = nt;
      if (cnti <= 512) break;
    }
    if (!fixed) {
      if (cnti <= 512) {
        int base = 0;
#pragma unroll
        for (int i = 0; i < 8; ++i)
#pragma unroll
          for (int j = 0; j < 4; ++j) {
            bool a = x[i][j] > tau;
            unsigned long long mk = __ballot(a);
            if (a) comp[wv][base + (int)__builtin_popcountll(mk & lmask)] = x[i][j];
            base += (int)__builtin_popcountll(mk);
          }
        float y[8];
#pragma unroll
        for (int r = 0; r < 8; ++r) {
          int idx = r * 64 + l;
          y[r] = (idx < base) ? comp[wv][idx] : -2.0f;  // sentinel < -1 <= tau
        }
        for (int it = 0; it < 10 && !fixed; ++it) {
          float s1 = 0.f, s2 = 0.f;
          int c = 0;
#pragma unroll
          for (int r = 0; r < 8; ++r) {
            bool a = y[r] > tau;
            c += (int)__builtin_popcountll(__ballot(a));
            float sel = a ? y[r] : 0.f;
            s1 += sel;
            s2 = fmaf(sel, sel, s2);
          }
#pragma unroll
          for (int off = 32; off > 0; off >>= 1) {
            s1 += __shfl_xor(s1, off, 64);
            s2 += __shfl_xor(s2, off, 64);
          }
          float cnt = (float)c;
          float mean = s1 / cnt;
          float ss = s2 - s1 * mean;
          float nt = mean - sqrtf(fmaxf((1.0f - ss) / cnt, 0.0f));
          if (nt == tau) fixed = true;
          else tau = nt;
        }
      } else {
        for (int it = 0; it < 8 && !fixed; ++it) {
          float s1 = 0.f, s2 = 0.f;
          int c = 0;
#pragma unroll
          for (int i = 0; i < 8; ++i)
#pragma unroll
            for (int j = 0; j < 4; ++j) {
              bool a = x[i][j] > tau;
              c += (int)__builtin_popcountll(__ballot(a));
              float sel = a ? x[i][j] : 0.f;
              s1 += sel;
              s2 = fmaf(sel, sel, s2);
            }
#pragma unroll
          for (int off = 32; off > 0; off >>= 1) {
            s1 += __shfl_xor(s1, off, 64);
            s2 += __shfl_xor(s2, off, 64);
          }
          float cnt = (float)c;
          float mean = s1 / cnt;
          float ss = s2 - s1 * mean;
          float nt = mean - sqrtf(fmaxf((1.0f - ss) / cnt, 0.0f));
          if (nt == tau) fixed = true;
          else tau = nt;
        }
      }
    }
    if (l == 0) cs[row] = 0.5f * m + tau;
  }
  __syncthreads();

  // ---- phase 3: xi = w @ V  (wave wv covers output cols [wv*32, wv*32+32))
  _Float16 ch = (_Float16)cs[lr];  // c for row m = lr
  fv4 acc2[2] = {{}, {}};
  int nbase = wv * 32;
  for (int k0 = 0; k0 < 2048; k0 += 32) {
    half8 s8 = *(const half8*)&Ss[lr * SST + k0 + quad * 8];
    half8 d = s8 * (_Float16)0.5f - ch;
    d = __builtin_elementwise_max(d, (half8)(0));
    half8 w8 = d * d;
#pragma unroll
    for (int ni = 0; ni < 2; ++ni) {
      half8 bf = *(const half8*)(Vb + (size_t)(nbase + ni * 16 + lr) * 2048 + k0 + quad * 8);
      acc2[ni] = __builtin_amdgcn_mfma_f32_16x16x32_f16(w8, bf, acc2[ni], 0, 0, 0);
    }
  }
  _Float16* xo = xout + ((size_t)(b * 1024 + strip * 16)) * 1024 + h * 128;
#pragma unroll
  for (int ni = 0; ni < 2; ++ni)
#pragma unroll
    for (int r = 0; r < 4; ++r)
      xo[(size_t)(quad * 4 + r) * 1024 + nbase + ni * 16 + lr] = (_Float16)acc2[ni][r];
}

// ---------------------------------------------------------------- generic NT GEMM
// C[M,N] = alpha * A[M,K] @ B[N,K]^T.  128x128 tile, 4 waves, 4x4 16x16x32 f16 MFMA.
// nsplit>1: blockIdx.x = ntile*nsplit + kchunk; partial fp32 out at C32 + ks*partStride.
// dual: blockIdx.z selects job {B,outMode} vs {B2,outModeB}.
// outMode 0: fp16   1: fp32
struct GemmParams {
  const _Float16 *A, *B, *B2;
  _Float16 *C16, *C16b;
  float* C32;
  int K, lda, ldb;
  long long cOsR, cOsC;
  long long cOsRb, cOsCb;
  long long partStride;
  int outMode, outModeB, nsplit, dual;
};

__global__ __launch_bounds__(256) void gemm_nt(GemmParams p) {
  __shared__ __align__(16) _Float16 As[128 * 32];
  __shared__ __align__(16) _Float16 Bs[128 * 32];
  int t = threadIdx.x;
  int m0 = blockIdx.y * 128;
  int bx = blockIdx.x, n0, kbeg, kend, ks = 0;
  if (p.nsplit > 1) {
    ks = bx % p.nsplit;
    n0 = (bx / p.nsplit) * 128;
    int kl = p.K / p.nsplit;
    kbeg = ks * kl;
    kend = kbeg + kl;
  } else {
    n0 = bx * 128;
    kbeg = 0;
    kend = p.K;
  }
  int job = p.dual ? blockIdx.z : 0;
  const _Float16* pA = p.A;
  const _Float16* pB = job ? p.B2 : p.B;

  fv4 acc[4][4] = {};
  int wv = t >> 6, l = t & 63, quad = l >> 4, lr = l & 15;
  int wm = (wv >> 1) * 64, wn = (wv & 1) * 64;
  int rl = l >> 2, cl = (l & 3) * 8;

  for (int k0 = kbeg; k0 < kend; k0 += 32) {
#pragma unroll
    for (int v = 0; v < 2; ++v) {
      int rb = wv * 16 + v * 64;
      int r = rb + rl;
      gll16(pA + (size_t)(m0 + r) * p.lda + k0 + cl, &As[rb * 32]);
      gll16(pB + (size_t)(n0 + r) * p.ldb + k0 + cl, &Bs[rb * 32]);
    }
    __syncthreads();
    half8 ah[4], bh[4];
#pragma unroll
    for (int mi = 0; mi < 4; ++mi) ah[mi] = *(const half8*)&As[(wm + mi * 16 + lr) * 32 + quad * 8];
#pragma unroll
    for (int ni = 0; ni < 4; ++ni) bh[ni] = *(const half8*)&Bs[(wn + ni * 16 + lr) * 32 + quad * 8];
#pragma unroll
    for (int mi = 0; mi < 4; ++mi)
#pragma unroll
      for (int ni = 0; ni < 4; ++ni)
        acc[mi][ni] = __builtin_amdgcn_mfma_f32_16x16x32_f16(ah[mi], bh[ni], acc[mi][ni], 0, 0, 0);
    __syncthreads();
  }

  int om = (p.dual && job) ? p.outModeB : p.outMode;
  _Float16* c16 = (p.dual && job) ? p.C16b : p.C16;
  long long osR = (p.dual && job) ? p.cOsRb : p.cOsR;
  long long osC = (p.dual && job) ? p.cOsCb : p.cOsC;
  float* c32 = p.C32 + (p.nsplit > 1 ? (long long)ks * p.partStride : 0);
#pragma unroll
  for (int mi = 0; mi < 4; ++mi)
#pragma unroll
    for (int ni = 0; ni < 4; ++ni) {
      int row = m0 + wm + mi * 16 + quad * 4;
      int col = n0 + wn + ni * 16 + lr;
#pragma unroll
      for (int r = 0; r < 4; ++r) {
        float val = acc[mi][ni][r];
        long long idx = (long long)(row + r) * osR + (long long)col * osC;
        if (om == 1) c32[idx] = val;
        else c16[idx] = (_Float16)val;
      }
    }
}

// ---------------------------------------------------------------- host
extern "C" void kernel_launch(void* const* d_in, const int* in_sizes, int n_in,
                              void* d_out, int out_size, void* d_ws, size_t ws_size,
                              hipStream_t stream) {
  const float* hidden = (const float*)d_in[0];   // (2,1024,2048)
  const float* memory = (const float*)d_in[1];   // (2048,1024)
  const float* Wq = (const float*)d_in[2];       // (1024,2048)
  const float* Wk = (const float*)d_in[3];       // (1024,1024)
  const float* Wv = (const float*)d_in[4];       // (1024,1024)
  const float* Wo = (const float*)d_in[5];       // (2048,1024)
  const float* log_beta = (const float*)d_in[6]; // (8,)
  const float* g_state = (const float*)d_in[7];
  const float* b_state = (const float*)d_in[8];
  const float* g_mem = (const float*)d_in[9];
  const float* b_mem = (const float*)d_in[10];

  char* w = (char*)d_ws;
  auto alloc = [&](size_t bytes) {
    char* r = w;
    w += (bytes + 255) & ~(size_t)255;
    return r;
  };
  _Float16* wq16 = (_Float16*)alloc(2097152 * 2);
  _Float16* wk16 = (_Float16*)alloc(1048576 * 2);
  _Float16* wv16 = (_Float16*)alloc(1048576 * 2);
  _Float16* wo16 = (_Float16*)alloc(2097152 * 2);
  _Float16* lnh16 = (_Float16*)alloc(4194304 * 2);
  _Float16* mn16 = (_Float16*)alloc(2097152 * 2);
  _Float16* kph = (_Float16*)alloc(2097152 * 2);   // K proj (n, h*128+d)
  _Float16* vt16 = (_Float16*)alloc(2097152 * 2);  // V^T (h*128+d, n)
  _Float16* xih = (_Float16*)alloc(2097152 * 2);   // xi (b*S+s, h*128+d)
  float* parts = (float*)alloc((size_t)2 * 2097152 * 4);  // split-K partials (Q gemm)

  ln_rows<<<2048, 256, 0, stream>>>(hidden, g_state, b_state, lnh16, 2048);
  ln_rows<<<2048, 256, 0, stream>>>(memory, g_mem, b_mem, mn16, 1024);
  cast_f16<<<2048, 256, 0, stream>>>(Wq, wq16, 2097152);
  cast_f16<<<1024, 256, 0, stream>>>(Wk, wk16, 1048576);
  cast_f16<<<1024, 256, 0, stream>>>(Wv, wv16, 1048576);
  cast_f16<<<2048, 256, 0, stream>>>(Wo, wo16, 2097152);

  // Q = ln(hidden) @ Wq^T  (split-K=2 partials -> reduce -> xi fp16)
  {
    GemmParams p{};
    p.A = lnh16; p.lda = 2048;
    p.B = wq16; p.ldb = 2048;
    p.K = 2048; p.nsplit = 2;
    p.C32 = parts; p.outMode = 1; p.partStride = 2097152;
    p.cOsR = 1024; p.cOsC = 1;
    gemm_nt<<<dim3(16, 16, 1), 256, 0, stream>>>(p);
    reduce_split<<<2048, 256, 0, stream>>>(parts, 2, 2097152, xih, 2097152);
  }
  // K & V projections in one dual-job launch (both plain fp16)
  {
    GemmParams p{};
    p.A = mn16; p.lda = 1024;
    p.B = wk16; p.B2 = wv16; p.ldb = 1024;
    p.K = 1024; p.dual = 1;
    p.C16 = kph; p.outMode = 0; p.cOsR = 1024; p.cOsC = 1;
    p.C16b = vt16; p.outModeB = 0; p.cOsRb = 1; p.cOsCb = 2048;
    gemm_nt<<<dim3(8, 16, 2), 256, 0, stream>>>(p);
  }

  // 3 fused Hopfield steps (in-place xi update)
  for (int step = 0; step < 3; ++step)
    hop_step<<<dim3(64, 8, 2), 256, 0, stream>>>(xih, kph, vt16, log_beta, xih);

  // out = xi @ Wo^T  (fp32 out)
  {
    GemmParams p{};
    p.A = xih; p.lda = 1024;
    p.B = wo16; p.ldb = 1024;
    p.K = 1024;
    p.C32 = (float*)d_out; p.outMode = 1;
    p.cOsR = 2048; p.cOsC = 1;
    gemm_nt<<<dim3(16, 16, 1), 256, 0, stream>>>(p);
  }
}